// Round 4
// baseline (1358.385 us; speedup 1.0000x reference)
//
#include <hip/hip_runtime.h>
#include <hip/hip_bf16.h>

// ParallelCAttention on MI355X. All device I/O is f32 (matches reference dtype).
// B=8, CIN=256, COUT=64, CQK=8, padded V=T=128 (V0=T0=126).
//
// Pipeline (14 launches, one stream):
//  prep_w      : av_w (c,d,3,3) -> f32 [(d*9+tap)*64+c]
//  dc_conv     : y = conv1x1(pad(x), dc_w)+dc_b           (f32, b,c,v,t)
//  conv1x1 x3  : q,k (8ch, + transposed copies), v (+vT)
//  attn_stage A: per (b,t): E_H=Q^T K (diag mask), m/s, U_H = exp(E-m)V
//  attn_stage B: per (b,v): E_W, m/s, U_W
//  stage_c     : joint-softmax merge -> X1 = gamma*(out_H+out_W)
//  conv1x1 x3  : qc,kc,vc
//  chan_attn   : per (b,v): softmax_d(qc.kc^T) @ vc -> av
//  conv3x3+mix : out = y + X1 + sigma*conv3x3(av)

namespace {

// ---------------- prep weights for conv3x3 ----------------
__global__ __launch_bounds__(256) void prep_w_kernel(const float* __restrict__ avw,
                                                     float* __restrict__ wf)
{
  int idx = blockIdx.x * 256 + threadIdx.x;
  if (idx >= 64 * 64 * 9) return;
  int tap = idx % 9;
  int cd  = idx / 9;
  int d = cd & 63, c = cd >> 6;            // input layout (c, d, dv, dt)
  wf[(d * 9 + tap) * 64 + c] = avw[idx];
}

// ---------------- y = conv1x1(pad(x), dc_w) + dc_b ----------------
__global__ __launch_bounds__(256) void dc_conv_kernel(const float* __restrict__ x,
                                                      const float* __restrict__ w,
                                                      const float* __restrict__ bias,
                                                      float* __restrict__ y)
{
  int blk = blockIdx.x; int b = blk >> 6; int rp = blk & 63;
  int tid = threadIdx.x;
  int vv = rp * 2 + (tid >> 7); int tt = tid & 127;
  bool interior = (vv >= 1) && (vv <= 126) && (tt >= 1) && (tt <= 126);
  size_t xbase = 0;
  if (interior) xbase = (size_t)b * 256 * 15876 + (size_t)(vv - 1) * 126 + (tt - 1);
  __shared__ float xs[8 * 256];
  __shared__ float wsh[8 * 64];            // [i][o]
  float acc[64];
#pragma unroll
  for (int o = 0; o < 64; o++) acc[o] = 0.f;
#pragma unroll 1
  for (int cc = 0; cc < 256; cc += 8) {
#pragma unroll
    for (int i = 0; i < 8; i++) {
      float val = 0.f;
      if (interior) val = x[xbase + (size_t)(cc + i) * 15876];
      xs[i * 256 + tid] = val;
    }
    for (int f = tid; f < 512; f += 256) {
      int i = f >> 6; int o = f & 63;
      wsh[i * 64 + o] = w[o * 256 + cc + i];
    }
    __syncthreads();
#pragma unroll
    for (int i = 0; i < 8; i++) {
      float a = xs[i * 256 + tid];
      const float4* w4 = (const float4*)&wsh[i * 64];
#pragma unroll
      for (int o4 = 0; o4 < 16; o4++) {
        float4 wv = w4[o4];
        acc[o4 * 4 + 0] += a * wv.x; acc[o4 * 4 + 1] += a * wv.y;
        acc[o4 * 4 + 2] += a * wv.z; acc[o4 * 4 + 3] += a * wv.w;
      }
    }
    __syncthreads();
  }
  int p = (vv << 7) + tt;
  float* yb = y + ((size_t)b * 64 << 14) + p;
#pragma unroll
  for (int o = 0; o < 64; o++)
    yb[(size_t)o << 14] = acc[o] + bias[o];
}

// ---------------- generic conv1x1 from y (f32 in, f32 out, 64-ch input) -------
template <int O, bool WRITE_T>
__global__ __launch_bounds__(256) void conv1x1_kernel(const float* __restrict__ in,
                                                      const float* __restrict__ w,
                                                      const float* __restrict__ bias,
                                                      float* __restrict__ out,
                                                      float* __restrict__ outT)
{
  int blk = blockIdx.x; int b = blk >> 6; int rp = blk & 63;
  int tid = threadIdx.x;
  int vv = rp * 2 + (tid >> 7); int tt = tid & 127;
  int p = (vv << 7) + tt;
  __shared__ float ys[8 * 256];
  __shared__ float wsh[8 * O];             // [i][o]
  float acc[O];
#pragma unroll
  for (int o = 0; o < O; o++) acc[o] = 0.f;
  const float* inb = in + ((size_t)b * 64 << 14);
#pragma unroll 1
  for (int cc = 0; cc < 64; cc += 8) {
#pragma unroll
    for (int i = 0; i < 8; i++) ys[i * 256 + tid] = inb[((size_t)(cc + i) << 14) + p];
    for (int f = tid; f < 8 * O; f += 256) {
      int i = f / O; int o = f - i * O;
      wsh[f] = w[o * 64 + cc + i];
    }
    __syncthreads();
#pragma unroll
    for (int i = 0; i < 8; i++) {
      float a = ys[i * 256 + tid];
      const float4* w4 = (const float4*)&wsh[i * O];
#pragma unroll
      for (int o4 = 0; o4 < O / 4; o4++) {
        float4 wv = w4[o4];
        acc[o4 * 4 + 0] += a * wv.x; acc[o4 * 4 + 1] += a * wv.y;
        acc[o4 * 4 + 2] += a * wv.z; acc[o4 * 4 + 3] += a * wv.w;
      }
    }
    __syncthreads();
  }
#pragma unroll
  for (int o = 0; o < O; o++) {
    float r = acc[o] + bias[o];
    out[((size_t)(b * O + o) << 14) + p] = r;
    if (WRITE_T) outT[(((size_t)(b * 128 + tt) * O + o) << 7) + vv] = r;  // (b,t,c,pos)
  }
}

// ---------------- flash-style attention stage (shared for H and W axes) -------
// Per block g=(b,ii): E[r][u] = sum_c q[c][r]*k[c][u] (optional diag mask);
// m[r],s[r] local softmax stats; U[r][c] = sum_u exp(E-m) * v[c][u].
template <bool MASK>
__global__ __launch_bounds__(256) void attn_stage_kernel(const float* __restrict__ qP,
                                                         const float* __restrict__ kP,
                                                         const float* __restrict__ vP,
                                                         int QB, int QI, int QC,
                                                         int VB, int VI, int VC,
                                                         float* __restrict__ U,
                                                         float* __restrict__ mG,
                                                         float* __restrict__ sG)
{
  int g = blockIdx.x; int b = g >> 7; int ii = g & 127;
  int tid = threadIdx.x;
  __shared__ float qsT[128 * 12];          // [pos][c], stride 12 (16B-aligned rows)
  __shared__ float ksT[128 * 12];
  __shared__ float Ps[32 * 132];           // P chunk, stride 132 (16B-aligned rows)
  __shared__ float ms[128];
  const float* qb = qP + (size_t)b * QB + (size_t)ii * QI;
  const float* kb = kP + (size_t)b * QB + (size_t)ii * QI;
  for (int f = tid; f < 1024; f += 256) {
    int c = f >> 7; int j = f & 127;
    qsT[j * 12 + c] = qb[(size_t)c * QC + j];
    ksT[j * 12 + c] = kb[(size_t)c * QC + j];
  }
  __syncthreads();
  {
    int r = tid >> 1; int half = tid & 1; int u0 = half << 6;
    float4 qa  = *(const float4*)&qsT[r * 12];
    float4 qb4 = *(const float4*)&qsT[r * 12 + 4];
    float mloc = -1e30f;
    for (int du = 0; du < 64; du++) {
      int u = u0 + du;
      const float4* kp = (const float4*)&ksT[u * 12];
      float4 ka = kp[0], kb2 = kp[1];
      float e = qa.x * ka.x + qa.y * ka.y + qa.z * ka.z + qa.w * ka.w
              + qb4.x * kb2.x + qb4.y * kb2.y + qb4.z * kb2.z + qb4.w * kb2.w;
      if (!(MASK && u == r)) mloc = fmaxf(mloc, e);
    }
    float M = fmaxf(mloc, __shfl_xor(mloc, 1));
    float sloc = 0.f;
    for (int du = 0; du < 64; du++) {
      int u = u0 + du;
      const float4* kp = (const float4*)&ksT[u * 12];
      float4 ka = kp[0], kb2 = kp[1];
      float e = qa.x * ka.x + qa.y * ka.y + qa.z * ka.z + qa.w * ka.w
              + qb4.x * kb2.x + qb4.y * kb2.y + qb4.z * kb2.z + qb4.w * kb2.w;
      if (!(MASK && u == r)) sloc += __expf(e - M);
    }
    float stot = sloc + __shfl_xor(sloc, 1);
    if (half == 0) { ms[r] = M; mG[(g << 7) + r] = M; sG[(g << 7) + r] = stot; }
  }
  __syncthreads();
  int c = tid & 63; int w = tid >> 6;
  const float4* v4 = (const float4*)(vP + (size_t)b * VB + (size_t)ii * VI + (size_t)c * VC);
  float acc[32];
#pragma unroll
  for (int j = 0; j < 32; j++) acc[j] = 0.f;
#pragma unroll
  for (int chk = 0; chk < 4; chk++) {
    int rbase = chk << 5;
    for (int f = tid; f < 4096; f += 256) {
      int rr = f >> 7; int u = f & 127; int r = rbase + rr;
      const float4* qp = (const float4*)&qsT[r * 12];
      const float4* kp = (const float4*)&ksT[u * 12];
      float4 qa = qp[0], qb4 = qp[1], ka = kp[0], kb2 = kp[1];
      float e = qa.x * ka.x + qa.y * ka.y + qa.z * ka.z + qa.w * ka.w
              + qb4.x * kb2.x + qb4.y * kb2.y + qb4.z * kb2.z + qb4.w * kb2.w;
      float pv;
      if (MASK && u == r) pv = 0.f; else pv = __expf(e - ms[r]);
      Ps[rr * 132 + u] = pv;
    }
    __syncthreads();
    for (int u4 = 0; u4 < 32; u4++) {
      float4 vvv = v4[u4];
      int ub = u4 << 2;
#pragma unroll
      for (int jj = 0; jj < 8; jj++) {
        const float* pr = &Ps[(w + (jj << 2)) * 132 + ub];
        acc[(chk << 3) + jj] += pr[0] * vvv.x + pr[1] * vvv.y + pr[2] * vvv.z + pr[3] * vvv.w;
      }
    }
    __syncthreads();
  }
#pragma unroll
  for (int j = 0; j < 32; j++) {
    int c2 = j >> 3; int jj = j & 7;
    int r = (c2 << 5) + w + (jj << 2);
    U[((size_t)(g << 7) + r) * 64 + c] = acc[j];
  }
}

// ---------------- joint-softmax merge: X1 = gamma*(out_H+out_W) ----------------
__global__ __launch_bounds__(256) void stage_c_kernel(const float* __restrict__ UH,
                                                      const float* __restrict__ UW,
                                                      const float* __restrict__ mH,
                                                      const float* __restrict__ sH,
                                                      const float* __restrict__ mW,
                                                      const float* __restrict__ sW,
                                                      const float* __restrict__ gammaP,
                                                      float* __restrict__ X1)
{
  int g = blockIdx.x; int b = g >> 7; int v = g & 127;
  int tid = threadIdx.x; int t = tid & 127; int c0 = tid >> 7;
  float gam = gammaP[0];
  int idxH = ((b << 7) + t) * 128 + v;     // (b,t,v)
  int idxW = (g << 7) + t;                 // (b,v,t)
  float mh = mH[idxH], sh = sH[idxH];
  float mw = mW[idxW], sw = sW[idxW];
  float M = fmaxf(mh, mw);
  float ea = __expf(mh - M), eb = __expf(mw - M);
  float denom = sh * ea + sw * eb;
  float fA = gam * ea / denom, fB = gam * eb / denom;
  const float* uh = UH + (size_t)idxH * 64;
  const float* uw = UW + (size_t)idxW * 64;
  float* x1p = X1 + ((size_t)b * 64 << 14) + (v << 7) + t;
#pragma unroll
  for (int j = 0; j < 32; j++) {
    int c = c0 + (j << 1);
    x1p[(size_t)c << 14] = fA * uh[c] + fB * uw[c];
  }
}

// ---------------- channel attention: av = softmax_d(qc.kc^T) @ vc --------------
__global__ __launch_bounds__(256) void chan_attn_kernel(const float* __restrict__ qc,
                                                        const float* __restrict__ kc,
                                                        const float* __restrict__ vcp,
                                                        float* __restrict__ av)
{
  int g = blockIdx.x; int b = g >> 7; int v = g & 127;
  int tid = threadIdx.x;
  __shared__ float smem[128 * 68];         // qc rows [c][t]@130, then vc^T [t][d]@68
  __shared__ float Ps[64 * 68];            // logits/probs [c][d]@68
  size_t base = ((size_t)b * 64 << 14) + (v << 7);
  for (int f = tid; f < 8192; f += 256) {
    int c = f >> 7, t = f & 127;
    smem[c * 130 + t] = qc[base + ((size_t)c << 14) + t];
  }
  __syncthreads();
  {
    int d = tid & 63, w = tid >> 6;
    const float4* k4 = (const float4*)(kc + base + ((size_t)d << 14));
#pragma unroll 1
    for (int j = 0; j < 16; j++) {
      int c = w + (j << 2);
      const float* qrow = &smem[c * 130];
      float e = 0.f;
#pragma unroll
      for (int t4 = 0; t4 < 32; t4++) {
        float4 kv = k4[t4];
        const float* qp = qrow + (t4 << 2);
        e += qp[0] * kv.x + qp[1] * kv.y + qp[2] * kv.z + qp[3] * kv.w;
      }
      Ps[c * 68 + d] = e;
    }
  }
  __syncthreads();
  if (tid < 64) {
    int c = tid;
    float m = -1e30f;
#pragma unroll 1
    for (int d = 0; d < 64; d++) m = fmaxf(m, Ps[c * 68 + d]);
    float s = 0.f;
#pragma unroll 1
    for (int d = 0; d < 64; d++) { float p = __expf(Ps[c * 68 + d] - m); Ps[c * 68 + d] = p; s += p; }
    float inv = 1.0f / s;
#pragma unroll 1
    for (int d = 0; d < 64; d++) Ps[c * 68 + d] *= inv;
  }
  __syncthreads();
  for (int f = tid; f < 8192; f += 256) {  // stage vc transposed [t][d]
    int d = f >> 7, t = f & 127;
    smem[t * 68 + d] = vcp[base + ((size_t)d << 14) + t];
  }
  __syncthreads();
  {
    int t = tid & 127, chh = tid >> 7;
    float4 vreg[16];
    const float4* vt4 = (const float4*)&smem[t * 68];
#pragma unroll
    for (int d4 = 0; d4 < 16; d4++) vreg[d4] = vt4[d4];
#pragma unroll 1
    for (int j = 0; j < 32; j++) {
      int c = chh + (j << 1);
      const float4* p4 = (const float4*)&Ps[c * 68];
      float a = 0.f;
#pragma unroll
      for (int d4 = 0; d4 < 16; d4++) {
        float4 pv = p4[d4];
        a += pv.x * vreg[d4].x + pv.y * vreg[d4].y + pv.z * vreg[d4].z + pv.w * vreg[d4].w;
      }
      av[base + ((size_t)c << 14) + t] = a;
    }
  }
}

// ---------------- conv3x3 + final combine -> f32 out --------------------------
__global__ __launch_bounds__(256) void conv3x3_combine_kernel(const float* __restrict__ av,
                                                              const float* __restrict__ wf,
                                                              const float* __restrict__ y,
                                                              const float* __restrict__ X1,
                                                              const float* __restrict__ sigmaP,
                                                              float* __restrict__ out)
{
  int blk = blockIdx.x; int b = blk >> 6; int rp = blk & 63;
  int tid = threadIdx.x;
  int vv0 = rp << 1;
  int vv = vv0 + (tid >> 7); int tt = tid & 127;
  __shared__ float avs[8 * 520];           // [i][rr(4)][col(130)]
  __shared__ float wsm[8 * 9 * 64];        // [(i*9+tap)*64 + c]
  float acc[64];
#pragma unroll
  for (int c = 0; c < 64; c++) acc[c] = 0.f;
#pragma unroll 1
  for (int chk = 0; chk < 8; chk++) {
    int d0 = chk << 3;
    for (int f = tid; f < 4160; f += 256) {
      int i = f / 520; int rem = f - i * 520; int rr = rem / 130; int col = rem - rr * 130;
      int vr = vv0 - 1 + rr; int tin = col - 1;
      float val = 0.f;
      if ((unsigned)vr < 128u && (unsigned)tin < 128u)
        val = av[(((size_t)(b * 64 + d0 + i) << 7) + vr) * 128 + tin];
      avs[f] = val;
    }
    for (int f = tid; f < 4608; f += 256) wsm[f] = wf[d0 * 576 + f];
    __syncthreads();
    int r0 = tid >> 7;
#pragma unroll 1
    for (int i = 0; i < 8; i++) {
      float a[9];
#pragma unroll
      for (int dv = 0; dv < 3; dv++)
#pragma unroll
        for (int dt = 0; dt < 3; dt++)
          a[dv * 3 + dt] = avs[i * 520 + (r0 + dv) * 130 + tt + dt];
#pragma unroll
      for (int tap = 0; tap < 9; tap++) {
        const float4* w4 = (const float4*)&wsm[(i * 9 + tap) << 6];
        float aa = a[tap];
#pragma unroll
        for (int c4 = 0; c4 < 16; c4++) {
          float4 wv = w4[c4];
          acc[c4 * 4 + 0] += aa * wv.x; acc[c4 * 4 + 1] += aa * wv.y;
          acc[c4 * 4 + 2] += aa * wv.z; acc[c4 * 4 + 3] += aa * wv.w;
        }
      }
    }
    __syncthreads();
  }
  float sig = sigmaP[0];
  size_t pbase = ((size_t)b * 64 << 14) + (vv << 7) + tt;
#pragma unroll
  for (int c = 0; c < 64; c++) {
    size_t idx = pbase + ((size_t)c << 14);
    out[idx] = y[idx] + X1[idx] + sig * acc[c];
  }
}

} // namespace

extern "C" void kernel_launch(void* const* d_in, const int* in_sizes, int n_in,
                              void* d_out, int out_size, void* d_ws, size_t ws_size,
                              hipStream_t stream)
{
  (void)in_sizes; (void)n_in; (void)out_size;
  const float* x     = (const float*)d_in[0];
  const float* dcw   = (const float*)d_in[1];
  const float* dcb   = (const float*)d_in[2];
  const float* qw    = (const float*)d_in[3];
  const float* qbb   = (const float*)d_in[4];
  const float* kw    = (const float*)d_in[5];
  const float* kbb   = (const float*)d_in[6];
  const float* vw    = (const float*)d_in[7];
  const float* vbb   = (const float*)d_in[8];
  const float* gamma = (const float*)d_in[9];
  const float* cqw   = (const float*)d_in[10];
  const float* cqb   = (const float*)d_in[11];
  const float* ckw   = (const float*)d_in[12];
  const float* ckb   = (const float*)d_in[13];
  const float* cvw   = (const float*)d_in[14];
  const float* cvb   = (const float*)d_in[15];
  const float* avw   = (const float*)d_in[16];
  const float* sigma = (const float*)d_in[17];
  float* out = (float*)d_out;

  if (ws_size < 220348416ull) return;      // need ~210 MiB of f32 scratch

  float* ws  = (float*)d_ws;
  float* y   = ws;                         // (b,c,v,t)   8,388,608
  float* X1  = ws + 8388608;               // (b,c,v,t)
  float* q   = ws + 16777216;              // (b,8,v,t)
  float* k   = ws + 17825792;
  float* qT  = ws + 18874368;              // (b,t,8,v)
  float* kT  = ws + 19922944;
  float* v   = ws + 20971520;              // (b,c,v,t)
  float* vT  = ws + 29360128;              // (b,t,c,u)
  float* UH  = ws + 37748736;              // (b,t,v,c)
  float* UW  = ws + 46137344;              // (b,v,t,c)
  float* mH  = ws + 54525952;              // (b,t,v)
  float* sH  = ws + 54657024;
  float* mW  = ws + 54788096;              // (b,v,t)
  float* sW  = ws + 54919168;
  float* wf  = ws + 55050240;              // 36,864 f32 conv3x3 weights
  float* qc  = vT;                         // reuse (consumed before reuse)
  float* kc  = UH;
  float* vc  = UW;
  float* avb = v;

  prep_w_kernel<<<144, 256, 0, stream>>>(avw, wf);
  dc_conv_kernel<<<512, 256, 0, stream>>>(x, dcw, dcb, y);
  conv1x1_kernel<8,  true ><<<512, 256, 0, stream>>>(y, qw,  qbb, q,  qT);
  conv1x1_kernel<8,  true ><<<512, 256, 0, stream>>>(y, kw,  kbb, k,  kT);
  conv1x1_kernel<64, true ><<<512, 256, 0, stream>>>(y, vw,  vbb, v,  vT);
  // Stage A: per (b,t), qT/kT (b,t,c,v): QB=131072 QI=1024 QC=128; vT: VB=1048576 VI=8192 VC=128
  attn_stage_kernel<true ><<<1024, 256, 0, stream>>>(qT, kT, vT,
      131072, 1024, 128, 1048576, 8192, 128, UH, mH, sH);
  // Stage B: per (b,v), q/k (b,c,v,t): QB=131072 QI=128 QC=16384; v: VB=1048576 VI=128 VC=16384
  attn_stage_kernel<false><<<1024, 256, 0, stream>>>(q, k, v,
      131072, 128, 16384, 1048576, 128, 16384, UW, mW, sW);
  stage_c_kernel<<<1024, 256, 0, stream>>>(UH, UW, mH, sH, mW, sW, gamma, X1);
  conv1x1_kernel<64, false><<<512, 256, 0, stream>>>(y, cqw, cqb, qc, (float*)nullptr);
  conv1x1_kernel<64, false><<<512, 256, 0, stream>>>(y, ckw, ckb, kc, (float*)nullptr);
  conv1x1_kernel<64, false><<<512, 256, 0, stream>>>(y, cvw, cvb, vc, (float*)nullptr);
  chan_attn_kernel<<<1024, 256, 0, stream>>>(qc, kc, vc, avb);
  conv3x3_combine_kernel<<<512, 256, 0, stream>>>(avb, wf, y, X1, sigma, out);
}

// Round 6
// 1174.067 us; speedup vs baseline: 1.1570x; 1.1570x over previous
//
#include <hip/hip_runtime.h>
#include <hip/hip_bf16.h>

// ParallelCAttention on MI355X. All device I/O is f32 (matches reference dtype).
// B=8, CIN=256, COUT=64, CQK=8, padded V=T=128 (V0=T0=126).
//
// R6: fix wsm staging decode in conv3x3 (stride 288, not 256) — R5 regression.
// R5: occupancy re-grid of all conv kernels (1 row/block + channel split).

namespace {

// ---------------- prep weights for conv3x3 ----------------
__global__ __launch_bounds__(256) void prep_w_kernel(const float* __restrict__ avw,
                                                     float* __restrict__ wf)
{
  int idx = blockIdx.x * 256 + threadIdx.x;
  if (idx >= 64 * 64 * 9) return;
  int tap = idx % 9;
  int cd  = idx / 9;
  int d = cd & 63, c = cd >> 6;            // input layout (c, d, dv, dt)
  wf[(d * 9 + tap) * 64 + c] = avw[idx];
}

// ---------------- y = conv1x1(pad(x), dc_w) + dc_b ----------------
// grid: (b, v) = 1024 blocks; 256 thr = 128 cols x 2 out-ch halves (32 each)
__global__ __launch_bounds__(256) void dc_conv_kernel(const float* __restrict__ x,
                                                      const float* __restrict__ w,
                                                      const float* __restrict__ bias,
                                                      float* __restrict__ y)
{
  int blk = blockIdx.x; int b = blk >> 7; int v = blk & 127;
  int tid = threadIdx.x;
  int tt = tid & 127; int sub = tid >> 7;  // sub: out-channel half
  bool interior = (v >= 1) && (v <= 126) && (tt >= 1) && (tt <= 126);
  __shared__ float xs[8 * 128];
  __shared__ float wsh[8 * 64];            // [i][o]
  float acc[32];
#pragma unroll
  for (int o = 0; o < 32; o++) acc[o] = 0.f;
  size_t xrow = (size_t)b * 256 * 15876 + (size_t)(v - 1) * 126;
#pragma unroll 1
  for (int cc = 0; cc < 256; cc += 8) {
    for (int f = tid; f < 1024; f += 256) {
      int i = f >> 7; int col = f & 127;
      float val = 0.f;
      if ((v >= 1) && (v <= 126) && (col >= 1) && (col <= 126))
        val = x[xrow + (size_t)(cc + i) * 15876 + (col - 1)];
      xs[f] = val;
    }
    for (int f = tid; f < 512; f += 256) {
      int i = f >> 6; int o = f & 63;
      wsh[i * 64 + o] = w[o * 256 + cc + i];
    }
    __syncthreads();
    if (interior) {
#pragma unroll
      for (int i = 0; i < 8; i++) {
        float a = xs[i * 128 + tt];
        const float4* w4 = (const float4*)&wsh[i * 64 + sub * 32];
#pragma unroll
        for (int o4 = 0; o4 < 8; o4++) {
          float4 wv = w4[o4];
          acc[o4 * 4 + 0] += a * wv.x; acc[o4 * 4 + 1] += a * wv.y;
          acc[o4 * 4 + 2] += a * wv.z; acc[o4 * 4 + 3] += a * wv.w;
        }
      }
    }
    __syncthreads();
  }
  int p = (v << 7) + tt;
  float* yb = y + ((size_t)b * 64 << 14) + p;
#pragma unroll
  for (int o = 0; o < 32; o++) {
    int oc = sub * 32 + o;
    yb[(size_t)oc << 14] = acc[o] + bias[oc];
  }
}

// ---------------- generic conv1x1 from y (f32 in, f32 out, 64-ch input) -------
// grid: (b, v) = 1024 blocks; 256 thr = 128 cols x 2 out-ch halves (O/2 each)
template <int O, bool WRITE_T>
__global__ __launch_bounds__(256) void conv1x1_kernel(const float* __restrict__ in,
                                                      const float* __restrict__ w,
                                                      const float* __restrict__ bias,
                                                      float* __restrict__ out,
                                                      float* __restrict__ outT)
{
  constexpr int OH = O / 2;
  int blk = blockIdx.x; int b = blk >> 7; int v = blk & 127;
  int tid = threadIdx.x;
  int tt = tid & 127; int sub = tid >> 7;
  int p = (v << 7) + tt;
  __shared__ float ys[8 * 128];
  __shared__ float wsh[8 * O];             // [i][o]
  float acc[OH];
#pragma unroll
  for (int o = 0; o < OH; o++) acc[o] = 0.f;
  const float* inb = in + ((size_t)b * 64 << 14) + (v << 7);
#pragma unroll 1
  for (int cc = 0; cc < 64; cc += 8) {
    for (int f = tid; f < 1024; f += 256) {
      int i = f >> 7; int col = f & 127;
      ys[f] = inb[((size_t)(cc + i) << 14) + col];
    }
    for (int f = tid; f < 8 * O; f += 256) {
      int i = f / O; int o = f - i * O;
      wsh[f] = w[o * 64 + cc + i];
    }
    __syncthreads();
#pragma unroll
    for (int i = 0; i < 8; i++) {
      float a = ys[i * 128 + tt];
      const float4* w4 = (const float4*)&wsh[i * O + sub * OH];
#pragma unroll
      for (int o4 = 0; o4 < OH / 4; o4++) {
        float4 wv = w4[o4];
        acc[o4 * 4 + 0] += a * wv.x; acc[o4 * 4 + 1] += a * wv.y;
        acc[o4 * 4 + 2] += a * wv.z; acc[o4 * 4 + 3] += a * wv.w;
      }
    }
    __syncthreads();
  }
#pragma unroll
  for (int o = 0; o < OH; o++) {
    int oc = sub * OH + o;
    float r = acc[o] + bias[oc];
    out[((size_t)(b * O + oc) << 14) + p] = r;
    if (WRITE_T) outT[(((size_t)(b * 128 + tt) * O + oc) << 7) + v] = r;  // (b,t,c,pos)
  }
}

// ---------------- flash-style attention stage (shared for H and W axes) -------
// Per block g=(b,ii): E[r][u] = sum_c q[c][r]*k[c][u] (optional diag mask);
// m[r],s[r] local softmax stats; U[r][c] = sum_u exp(E-m) * v[c][u].
template <bool MASK>
__global__ __launch_bounds__(256) void attn_stage_kernel(const float* __restrict__ qP,
                                                         const float* __restrict__ kP,
                                                         const float* __restrict__ vP,
                                                         int QB, int QI, int QC,
                                                         int VB, int VI, int VC,
                                                         float* __restrict__ U,
                                                         float* __restrict__ mG,
                                                         float* __restrict__ sG)
{
  int g = blockIdx.x; int b = g >> 7; int ii = g & 127;
  int tid = threadIdx.x;
  __shared__ float qsT[128 * 12];          // [pos][c], stride 12 (16B-aligned rows)
  __shared__ float ksT[128 * 12];
  __shared__ float Ps[32 * 132];           // P chunk, stride 132 (16B-aligned rows)
  __shared__ float ms[128];
  const float* qb = qP + (size_t)b * QB + (size_t)ii * QI;
  const float* kb = kP + (size_t)b * QB + (size_t)ii * QI;
  for (int f = tid; f < 1024; f += 256) {
    int c = f >> 7; int j = f & 127;
    qsT[j * 12 + c] = qb[(size_t)c * QC + j];
    ksT[j * 12 + c] = kb[(size_t)c * QC + j];
  }
  __syncthreads();
  {
    int r = tid >> 1; int half = tid & 1; int u0 = half << 6;
    float4 qa  = *(const float4*)&qsT[r * 12];
    float4 qb4 = *(const float4*)&qsT[r * 12 + 4];
    float mloc = -1e30f;
    for (int du = 0; du < 64; du++) {
      int u = u0 + du;
      const float4* kp = (const float4*)&ksT[u * 12];
      float4 ka = kp[0], kb2 = kp[1];
      float e = qa.x * ka.x + qa.y * ka.y + qa.z * ka.z + qa.w * ka.w
              + qb4.x * kb2.x + qb4.y * kb2.y + qb4.z * kb2.z + qb4.w * kb2.w;
      if (!(MASK && u == r)) mloc = fmaxf(mloc, e);
    }
    float M = fmaxf(mloc, __shfl_xor(mloc, 1));
    float sloc = 0.f;
    for (int du = 0; du < 64; du++) {
      int u = u0 + du;
      const float4* kp = (const float4*)&ksT[u * 12];
      float4 ka = kp[0], kb2 = kp[1];
      float e = qa.x * ka.x + qa.y * ka.y + qa.z * ka.z + qa.w * ka.w
              + qb4.x * kb2.x + qb4.y * kb2.y + qb4.z * kb2.z + qb4.w * kb2.w;
      if (!(MASK && u == r)) sloc += __expf(e - M);
    }
    float stot = sloc + __shfl_xor(sloc, 1);
    if (half == 0) { ms[r] = M; mG[(g << 7) + r] = M; sG[(g << 7) + r] = stot; }
  }
  __syncthreads();
  int c = tid & 63; int w = tid >> 6;
  const float4* v4 = (const float4*)(vP + (size_t)b * VB + (size_t)ii * VI + (size_t)c * VC);
  float acc[32];
#pragma unroll
  for (int j = 0; j < 32; j++) acc[j] = 0.f;
#pragma unroll
  for (int chk = 0; chk < 4; chk++) {
    int rbase = chk << 5;
    for (int f = tid; f < 4096; f += 256) {
      int rr = f >> 7; int u = f & 127; int r = rbase + rr;
      const float4* qp = (const float4*)&qsT[r * 12];
      const float4* kp = (const float4*)&ksT[u * 12];
      float4 qa = qp[0], qb4 = qp[1], ka = kp[0], kb2 = kp[1];
      float e = qa.x * ka.x + qa.y * ka.y + qa.z * ka.z + qa.w * ka.w
              + qb4.x * kb2.x + qb4.y * kb2.y + qb4.z * kb2.z + qb4.w * kb2.w;
      float pv;
      if (MASK && u == r) pv = 0.f; else pv = __expf(e - ms[r]);
      Ps[rr * 132 + u] = pv;
    }
    __syncthreads();
    for (int u4 = 0; u4 < 32; u4++) {
      float4 vvv = v4[u4];
      int ub = u4 << 2;
#pragma unroll
      for (int jj = 0; jj < 8; jj++) {
        const float* pr = &Ps[(w + (jj << 2)) * 132 + ub];
        acc[(chk << 3) + jj] += pr[0] * vvv.x + pr[1] * vvv.y + pr[2] * vvv.z + pr[3] * vvv.w;
      }
    }
    __syncthreads();
  }
#pragma unroll
  for (int j = 0; j < 32; j++) {
    int c2 = j >> 3; int jj = j & 7;
    int r = (c2 << 5) + w + (jj << 2);
    U[((size_t)(g << 7) + r) * 64 + c] = acc[j];
  }
}

// ---------------- joint-softmax merge: X1 = gamma*(out_H+out_W) ----------------
__global__ __launch_bounds__(256) void stage_c_kernel(const float* __restrict__ UH,
                                                      const float* __restrict__ UW,
                                                      const float* __restrict__ mH,
                                                      const float* __restrict__ sH,
                                                      const float* __restrict__ mW,
                                                      const float* __restrict__ sW,
                                                      const float* __restrict__ gammaP,
                                                      float* __restrict__ X1)
{
  int g = blockIdx.x; int b = g >> 7; int v = g & 127;
  int tid = threadIdx.x; int t = tid & 127; int c0 = tid >> 7;
  float gam = gammaP[0];
  int idxH = ((b << 7) + t) * 128 + v;     // (b,t,v)
  int idxW = (g << 7) + t;                 // (b,v,t)
  float mh = mH[idxH], sh = sH[idxH];
  float mw = mW[idxW], sw = sW[idxW];
  float M = fmaxf(mh, mw);
  float ea = __expf(mh - M), eb = __expf(mw - M);
  float denom = sh * ea + sw * eb;
  float fA = gam * ea / denom, fB = gam * eb / denom;
  const float* uh = UH + (size_t)idxH * 64;
  const float* uw = UW + (size_t)idxW * 64;
  float* x1p = X1 + ((size_t)b * 64 << 14) + (v << 7) + t;
#pragma unroll
  for (int j = 0; j < 32; j++) {
    int c = c0 + (j << 1);
    x1p[(size_t)c << 14] = fA * uh[c] + fB * uw[c];
  }
}

// ---------------- channel attention: av = softmax_d(qc.kc^T) @ vc --------------
__global__ __launch_bounds__(256) void chan_attn_kernel(const float* __restrict__ qc,
                                                        const float* __restrict__ kc,
                                                        const float* __restrict__ vcp,
                                                        float* __restrict__ av)
{
  int g = blockIdx.x; int b = g >> 7; int v = g & 127;
  int tid = threadIdx.x;
  __shared__ float smem[128 * 68];         // qc rows [c][t]@130, then vc^T [t][d]@68
  __shared__ float Ps[64 * 68];            // logits/probs [c][d]@68
  size_t base = ((size_t)b * 64 << 14) + (v << 7);
  for (int f = tid; f < 8192; f += 256) {
    int c = f >> 7, t = f & 127;
    smem[c * 130 + t] = qc[base + ((size_t)c << 14) + t];
  }
  __syncthreads();
  {
    int d = tid & 63, w = tid >> 6;
    const float4* k4 = (const float4*)(kc + base + ((size_t)d << 14));
#pragma unroll 1
    for (int j = 0; j < 16; j++) {
      int c = w + (j << 2);
      const float* qrow = &smem[c * 130];
      float e = 0.f;
#pragma unroll
      for (int t4 = 0; t4 < 32; t4++) {
        float4 kv = k4[t4];
        const float* qp = qrow + (t4 << 2);
        e += qp[0] * kv.x + qp[1] * kv.y + qp[2] * kv.z + qp[3] * kv.w;
      }
      Ps[c * 68 + d] = e;
    }
  }
  __syncthreads();
  if (tid < 64) {
    int c = tid;
    float m = -1e30f;
#pragma unroll 1
    for (int d = 0; d < 64; d++) m = fmaxf(m, Ps[c * 68 + d]);
    float s = 0.f;
#pragma unroll 1
    for (int d = 0; d < 64; d++) { float p = __expf(Ps[c * 68 + d] - m); Ps[c * 68 + d] = p; s += p; }
    float inv = 1.0f / s;
#pragma unroll 1
    for (int d = 0; d < 64; d++) Ps[c * 68 + d] *= inv;
  }
  __syncthreads();
  for (int f = tid; f < 8192; f += 256) {  // stage vc transposed [t][d]
    int d = f >> 7, t = f & 127;
    smem[t * 68 + d] = vcp[base + ((size_t)d << 14) + t];
  }
  __syncthreads();
  {
    int t = tid & 127, chh = tid >> 7;
    float4 vreg[16];
    const float4* vt4 = (const float4*)&smem[t * 68];
#pragma unroll
    for (int d4 = 0; d4 < 16; d4++) vreg[d4] = vt4[d4];
#pragma unroll 1
    for (int j = 0; j < 32; j++) {
      int c = chh + (j << 1);
      const float4* p4 = (const float4*)&Ps[c * 68];
      float a = 0.f;
#pragma unroll
      for (int d4 = 0; d4 < 16; d4++) {
        float4 pv = p4[d4];
        a += pv.x * vreg[d4].x + pv.y * vreg[d4].y + pv.z * vreg[d4].z + pv.w * vreg[d4].w;
      }
      av[base + ((size_t)c << 14) + t] = a;
    }
  }
}

// ---------------- conv3x3 + final combine -> f32 out --------------------------
// grid: (b, v, half) = 2048 blocks; 256 thr = 128 cols x 2 sub-halves (16 ch each)
__global__ __launch_bounds__(256) void conv3x3_combine_kernel(const float* __restrict__ av,
                                                              const float* __restrict__ wf,
                                                              const float* __restrict__ y,
                                                              const float* __restrict__ X1,
                                                              const float* __restrict__ sigmaP,
                                                              float* __restrict__ out)
{
  int blk = blockIdx.x;
  int half = blk & 1;
  int v = (blk >> 1) & 127;
  int b = blk >> 8;
  int tid = threadIdx.x;
  int tt = tid & 127; int sub = tid >> 7;
  __shared__ float avs[8 * 390];           // [i][row(3)][col(130)]
  __shared__ float wsm[8 * 9 * 32];        // [i][tap][c-half], stride 288 per i
  float acc[16];
#pragma unroll
  for (int c = 0; c < 16; c++) acc[c] = 0.f;
#pragma unroll 1
  for (int chk = 0; chk < 8; chk++) {
    int d0 = chk << 3;
    for (int f = tid; f < 3120; f += 256) {
      int i = f / 390; int rem = f - i * 390; int rr = rem / 130; int col = rem - rr * 130;
      int vr = v - 1 + rr; int tin = col - 1;
      float val = 0.f;
      if ((unsigned)vr < 128u && (unsigned)tin < 128u)
        val = av[((size_t)(b * 64 + d0 + i) << 14) + (vr << 7) + tin];
      avs[f] = val;
    }
    for (int f = tid; f < 2304; f += 256) {
      int i = f / 288; int rem = f - i * 288; int tap = rem >> 5; int cc = rem & 31;
      wsm[f] = wf[((d0 + i) * 9 + tap) * 64 + half * 32 + cc];
    }
    __syncthreads();
#pragma unroll 1
    for (int i = 0; i < 8; i++) {
      float a[9];
#pragma unroll
      for (int dv = 0; dv < 3; dv++)
#pragma unroll
        for (int dt = 0; dt < 3; dt++)
          a[dv * 3 + dt] = avs[i * 390 + dv * 130 + tt + dt];
#pragma unroll
      for (int tap = 0; tap < 9; tap++) {
        const float4* w4 = (const float4*)&wsm[(i * 9 + tap) * 32 + sub * 16];
        float aa = a[tap];
#pragma unroll
        for (int c4 = 0; c4 < 4; c4++) {
          float4 wv = w4[c4];
          acc[c4 * 4 + 0] += aa * wv.x; acc[c4 * 4 + 1] += aa * wv.y;
          acc[c4 * 4 + 2] += aa * wv.z; acc[c4 * 4 + 3] += aa * wv.w;
        }
      }
    }
    __syncthreads();
  }
  float sig = sigmaP[0];
  int cbase = half * 32 + sub * 16;
  size_t pbase = ((size_t)b * 64 << 14) + (v << 7) + tt;
#pragma unroll
  for (int c = 0; c < 16; c++) {
    size_t idx = pbase + ((size_t)(cbase + c) << 14);
    out[idx] = y[idx] + X1[idx] + sig * acc[c];
  }
}

} // namespace

extern "C" void kernel_launch(void* const* d_in, const int* in_sizes, int n_in,
                              void* d_out, int out_size, void* d_ws, size_t ws_size,
                              hipStream_t stream)
{
  (void)in_sizes; (void)n_in; (void)out_size;
  const float* x     = (const float*)d_in[0];
  const float* dcw   = (const float*)d_in[1];
  const float* dcb   = (const float*)d_in[2];
  const float* qw    = (const float*)d_in[3];
  const float* qbb   = (const float*)d_in[4];
  const float* kw    = (const float*)d_in[5];
  const float* kbb   = (const float*)d_in[6];
  const float* vw    = (const float*)d_in[7];
  const float* vbb   = (const float*)d_in[8];
  const float* gamma = (const float*)d_in[9];
  const float* cqw   = (const float*)d_in[10];
  const float* cqb   = (const float*)d_in[11];
  const float* ckw   = (const float*)d_in[12];
  const float* ckb   = (const float*)d_in[13];
  const float* cvw   = (const float*)d_in[14];
  const float* cvb   = (const float*)d_in[15];
  const float* avw   = (const float*)d_in[16];
  const float* sigma = (const float*)d_in[17];
  float* out = (float*)d_out;

  if (ws_size < 220348416ull) return;      // need ~210 MiB of f32 scratch

  float* ws  = (float*)d_ws;
  float* y   = ws;                         // (b,c,v,t)   8,388,608
  float* X1  = ws + 8388608;               // (b,c,v,t)
  float* q   = ws + 16777216;              // (b,8,v,t)
  float* k   = ws + 17825792;
  float* qT  = ws + 18874368;              // (b,t,8,v)
  float* kT  = ws + 19922944;
  float* v   = ws + 20971520;              // (b,c,v,t)
  float* vT  = ws + 29360128;              // (b,t,c,u)
  float* UH  = ws + 37748736;              // (b,t,v,c)
  float* UW  = ws + 46137344;              // (b,v,t,c)
  float* mH  = ws + 54525952;              // (b,t,v)
  float* sH  = ws + 54657024;
  float* mW  = ws + 54788096;              // (b,v,t)
  float* sW  = ws + 54919168;
  float* wf  = ws + 55050240;              // 36,864 f32 conv3x3 weights
  float* qc  = vT;                         // reuse (consumed before reuse)
  float* kc  = UH;
  float* vc  = UW;
  float* avb = v;

  prep_w_kernel<<<144, 256, 0, stream>>>(avw, wf);
  dc_conv_kernel<<<1024, 256, 0, stream>>>(x, dcw, dcb, y);
  conv1x1_kernel<8,  true ><<<1024, 256, 0, stream>>>(y, qw,  qbb, q,  qT);
  conv1x1_kernel<8,  true ><<<1024, 256, 0, stream>>>(y, kw,  kbb, k,  kT);
  conv1x1_kernel<64, true ><<<1024, 256, 0, stream>>>(y, vw,  vbb, v,  vT);
  // Stage A: per (b,t), qT/kT (b,t,c,v): QB=131072 QI=1024 QC=128; vT: VB=1048576 VI=8192 VC=128
  attn_stage_kernel<true ><<<1024, 256, 0, stream>>>(qT, kT, vT,
      131072, 1024, 128, 1048576, 8192, 128, UH, mH, sH);
  // Stage B: per (b,v), q/k (b,c,v,t): QB=131072 QI=128 QC=16384; v: VB=1048576 VI=128 VC=16384
  attn_stage_kernel<false><<<1024, 256, 0, stream>>>(q, k, v,
      131072, 128, 16384, 1048576, 128, 16384, UW, mW, sW);
  stage_c_kernel<<<1024, 256, 0, stream>>>(UH, UW, mH, sH, mW, sW, gamma, X1);
  conv1x1_kernel<64, false><<<1024, 256, 0, stream>>>(y, cqw, cqb, qc, (float*)nullptr);
  conv1x1_kernel<64, false><<<1024, 256, 0, stream>>>(y, ckw, ckb, kc, (float*)nullptr);
  conv1x1_kernel<64, false><<<1024, 256, 0, stream>>>(y, cvw, cvb, vc, (float*)nullptr);
  chan_attn_kernel<<<1024, 256, 0, stream>>>(qc, kc, vc, avb);
  conv3x3_combine_kernel<<<2048, 256, 0, stream>>>(avb, wf, y, X1, sigma, out);
}

// Round 7
// 1038.118 us; speedup vs baseline: 1.3085x; 1.1310x over previous
//
#include <hip/hip_runtime.h>
#include <hip/hip_bf16.h>

// ParallelCAttention on MI355X. All device I/O is f32 (matches reference dtype).
// B=8, CIN=256, COUT=64, CQK=8, padded V=T=128 (V0=T0=126).
//
// R7: conv3x3 -> bf16 MFMA (9 taps x K=64, 18 mfma_16x16x32 per 16x16 tile);
//     prep_w now emits bf16 weights [o][tap][i]. Everything else unchanged.

namespace {

using short8 = __attribute__((ext_vector_type(8))) short;
using f32x4  = __attribute__((ext_vector_type(4))) float;

// ---------------- prep weights for conv3x3 (bf16, [o][tap][i]) ----------------
__global__ __launch_bounds__(256) void prep_w_kernel(const float* __restrict__ avw,
                                                     unsigned short* __restrict__ w2)
{
  int idx = blockIdx.x * 256 + threadIdx.x;
  if (idx >= 64 * 64 * 9) return;
  int o = idx / 576; int rem = idx - o * 576;
  int i = rem / 9;   int tap = rem - i * 9;
  __hip_bfloat16 h = __float2bfloat16(avw[idx]);
  w2[(o * 9 + tap) * 64 + i] = *(unsigned short*)&h;
}

// ---------------- y = conv1x1(pad(x), dc_w) + dc_b ----------------
// grid: (b, v) = 1024 blocks; 256 thr = 128 cols x 2 out-ch halves (32 each)
__global__ __launch_bounds__(256) void dc_conv_kernel(const float* __restrict__ x,
                                                      const float* __restrict__ w,
                                                      const float* __restrict__ bias,
                                                      float* __restrict__ y)
{
  int blk = blockIdx.x; int b = blk >> 7; int v = blk & 127;
  int tid = threadIdx.x;
  int tt = tid & 127; int sub = tid >> 7;  // sub: out-channel half
  bool interior = (v >= 1) && (v <= 126) && (tt >= 1) && (tt <= 126);
  __shared__ float xs[8 * 128];
  __shared__ float wsh[8 * 64];            // [i][o]
  float acc[32];
#pragma unroll
  for (int o = 0; o < 32; o++) acc[o] = 0.f;
  size_t xrow = (size_t)b * 256 * 15876 + (size_t)(v - 1) * 126;
#pragma unroll 1
  for (int cc = 0; cc < 256; cc += 8) {
    for (int f = tid; f < 1024; f += 256) {
      int i = f >> 7; int col = f & 127;
      float val = 0.f;
      if ((v >= 1) && (v <= 126) && (col >= 1) && (col <= 126))
        val = x[xrow + (size_t)(cc + i) * 15876 + (col - 1)];
      xs[f] = val;
    }
    for (int f = tid; f < 512; f += 256) {
      int i = f >> 6; int o = f & 63;
      wsh[i * 64 + o] = w[o * 256 + cc + i];
    }
    __syncthreads();
    if (interior) {
#pragma unroll
      for (int i = 0; i < 8; i++) {
        float a = xs[i * 128 + tt];
        const float4* w4 = (const float4*)&wsh[i * 64 + sub * 32];
#pragma unroll
        for (int o4 = 0; o4 < 8; o4++) {
          float4 wv = w4[o4];
          acc[o4 * 4 + 0] += a * wv.x; acc[o4 * 4 + 1] += a * wv.y;
          acc[o4 * 4 + 2] += a * wv.z; acc[o4 * 4 + 3] += a * wv.w;
        }
      }
    }
    __syncthreads();
  }
  int p = (v << 7) + tt;
  float* yb = y + ((size_t)b * 64 << 14) + p;
#pragma unroll
  for (int o = 0; o < 32; o++) {
    int oc = sub * 32 + o;
    yb[(size_t)oc << 14] = acc[o] + bias[oc];
  }
}

// ---------------- generic conv1x1 from y (f32 in, f32 out, 64-ch input) -------
// grid: (b, v) = 1024 blocks; 256 thr = 128 cols x 2 out-ch halves (O/2 each)
template <int O, bool WRITE_T>
__global__ __launch_bounds__(256) void conv1x1_kernel(const float* __restrict__ in,
                                                      const float* __restrict__ w,
                                                      const float* __restrict__ bias,
                                                      float* __restrict__ out,
                                                      float* __restrict__ outT)
{
  constexpr int OH = O / 2;
  int blk = blockIdx.x; int b = blk >> 7; int v = blk & 127;
  int tid = threadIdx.x;
  int tt = tid & 127; int sub = tid >> 7;
  int p = (v << 7) + tt;
  __shared__ float ys[8 * 128];
  __shared__ float wsh[8 * O];             // [i][o]
  float acc[OH];
#pragma unroll
  for (int o = 0; o < OH; o++) acc[o] = 0.f;
  const float* inb = in + ((size_t)b * 64 << 14) + (v << 7);
#pragma unroll 1
  for (int cc = 0; cc < 64; cc += 8) {
    for (int f = tid; f < 1024; f += 256) {
      int i = f >> 7; int col = f & 127;
      ys[f] = inb[((size_t)(cc + i) << 14) + col];
    }
    for (int f = tid; f < 8 * O; f += 256) {
      int i = f / O; int o = f - i * O;
      wsh[f] = w[o * 64 + cc + i];
    }
    __syncthreads();
#pragma unroll
    for (int i = 0; i < 8; i++) {
      float a = ys[i * 128 + tt];
      const float4* w4 = (const float4*)&wsh[i * O + sub * OH];
#pragma unroll
      for (int o4 = 0; o4 < OH / 4; o4++) {
        float4 wv = w4[o4];
        acc[o4 * 4 + 0] += a * wv.x; acc[o4 * 4 + 1] += a * wv.y;
        acc[o4 * 4 + 2] += a * wv.z; acc[o4 * 4 + 3] += a * wv.w;
      }
    }
    __syncthreads();
  }
#pragma unroll
  for (int o = 0; o < OH; o++) {
    int oc = sub * OH + o;
    float r = acc[o] + bias[oc];
    out[((size_t)(b * O + oc) << 14) + p] = r;
    if (WRITE_T) outT[(((size_t)(b * 128 + tt) * O + oc) << 7) + v] = r;  // (b,t,c,pos)
  }
}

// ---------------- flash-style attention stage (shared for H and W axes) -------
template <bool MASK>
__global__ __launch_bounds__(256) void attn_stage_kernel(const float* __restrict__ qP,
                                                         const float* __restrict__ kP,
                                                         const float* __restrict__ vP,
                                                         int QB, int QI, int QC,
                                                         int VB, int VI, int VC,
                                                         float* __restrict__ U,
                                                         float* __restrict__ mG,
                                                         float* __restrict__ sG)
{
  int g = blockIdx.x; int b = g >> 7; int ii = g & 127;
  int tid = threadIdx.x;
  __shared__ float qsT[128 * 12];          // [pos][c], stride 12 (16B-aligned rows)
  __shared__ float ksT[128 * 12];
  __shared__ float Ps[32 * 132];           // P chunk, stride 132 (16B-aligned rows)
  __shared__ float ms[128];
  const float* qb = qP + (size_t)b * QB + (size_t)ii * QI;
  const float* kb = kP + (size_t)b * QB + (size_t)ii * QI;
  for (int f = tid; f < 1024; f += 256) {
    int c = f >> 7; int j = f & 127;
    qsT[j * 12 + c] = qb[(size_t)c * QC + j];
    ksT[j * 12 + c] = kb[(size_t)c * QC + j];
  }
  __syncthreads();
  {
    int r = tid >> 1; int half = tid & 1; int u0 = half << 6;
    float4 qa  = *(const float4*)&qsT[r * 12];
    float4 qb4 = *(const float4*)&qsT[r * 12 + 4];
    float mloc = -1e30f;
    for (int du = 0; du < 64; du++) {
      int u = u0 + du;
      const float4* kp = (const float4*)&ksT[u * 12];
      float4 ka = kp[0], kb2 = kp[1];
      float e = qa.x * ka.x + qa.y * ka.y + qa.z * ka.z + qa.w * ka.w
              + qb4.x * kb2.x + qb4.y * kb2.y + qb4.z * kb2.z + qb4.w * kb2.w;
      if (!(MASK && u == r)) mloc = fmaxf(mloc, e);
    }
    float M = fmaxf(mloc, __shfl_xor(mloc, 1));
    float sloc = 0.f;
    for (int du = 0; du < 64; du++) {
      int u = u0 + du;
      const float4* kp = (const float4*)&ksT[u * 12];
      float4 ka = kp[0], kb2 = kp[1];
      float e = qa.x * ka.x + qa.y * ka.y + qa.z * ka.z + qa.w * ka.w
              + qb4.x * kb2.x + qb4.y * kb2.y + qb4.z * kb2.z + qb4.w * kb2.w;
      if (!(MASK && u == r)) sloc += __expf(e - M);
    }
    float stot = sloc + __shfl_xor(sloc, 1);
    if (half == 0) { ms[r] = M; mG[(g << 7) + r] = M; sG[(g << 7) + r] = stot; }
  }
  __syncthreads();
  int c = tid & 63; int w = tid >> 6;
  const float4* v4 = (const float4*)(vP + (size_t)b * VB + (size_t)ii * VI + (size_t)c * VC);
  float acc[32];
#pragma unroll
  for (int j = 0; j < 32; j++) acc[j] = 0.f;
#pragma unroll
  for (int chk = 0; chk < 4; chk++) {
    int rbase = chk << 5;
    for (int f = tid; f < 4096; f += 256) {
      int rr = f >> 7; int u = f & 127; int r = rbase + rr;
      const float4* qp = (const float4*)&qsT[r * 12];
      const float4* kp = (const float4*)&ksT[u * 12];
      float4 qa = qp[0], qb4 = qp[1], ka = kp[0], kb2 = kp[1];
      float e = qa.x * ka.x + qa.y * ka.y + qa.z * ka.z + qa.w * ka.w
              + qb4.x * kb2.x + qb4.y * kb2.y + qb4.z * kb2.z + qb4.w * kb2.w;
      float pv;
      if (MASK && u == r) pv = 0.f; else pv = __expf(e - ms[r]);
      Ps[rr * 132 + u] = pv;
    }
    __syncthreads();
    for (int u4 = 0; u4 < 32; u4++) {
      float4 vvv = v4[u4];
      int ub = u4 << 2;
#pragma unroll
      for (int jj = 0; jj < 8; jj++) {
        const float* pr = &Ps[(w + (jj << 2)) * 132 + ub];
        acc[(chk << 3) + jj] += pr[0] * vvv.x + pr[1] * vvv.y + pr[2] * vvv.z + pr[3] * vvv.w;
      }
    }
    __syncthreads();
  }
#pragma unroll
  for (int j = 0; j < 32; j++) {
    int c2 = j >> 3; int jj = j & 7;
    int r = (c2 << 5) + w + (jj << 2);
    U[((size_t)(g << 7) + r) * 64 + c] = acc[j];
  }
}

// ---------------- joint-softmax merge: X1 = gamma*(out_H+out_W) ----------------
__global__ __launch_bounds__(256) void stage_c_kernel(const float* __restrict__ UH,
                                                      const float* __restrict__ UW,
                                                      const float* __restrict__ mH,
                                                      const float* __restrict__ sH,
                                                      const float* __restrict__ mW,
                                                      const float* __restrict__ sW,
                                                      const float* __restrict__ gammaP,
                                                      float* __restrict__ X1)
{
  int g = blockIdx.x; int b = g >> 7; int v = g & 127;
  int tid = threadIdx.x; int t = tid & 127; int c0 = tid >> 7;
  float gam = gammaP[0];
  int idxH = ((b << 7) + t) * 128 + v;     // (b,t,v)
  int idxW = (g << 7) + t;                 // (b,v,t)
  float mh = mH[idxH], sh = sH[idxH];
  float mw = mW[idxW], sw = sW[idxW];
  float M = fmaxf(mh, mw);
  float ea = __expf(mh - M), eb = __expf(mw - M);
  float denom = sh * ea + sw * eb;
  float fA = gam * ea / denom, fB = gam * eb / denom;
  const float* uh = UH + (size_t)idxH * 64;
  const float* uw = UW + (size_t)idxW * 64;
  float* x1p = X1 + ((size_t)b * 64 << 14) + (v << 7) + t;
#pragma unroll
  for (int j = 0; j < 32; j++) {
    int c = c0 + (j << 1);
    x1p[(size_t)c << 14] = fA * uh[c] + fB * uw[c];
  }
}

// ---------------- channel attention: av = softmax_d(qc.kc^T) @ vc --------------
__global__ __launch_bounds__(256) void chan_attn_kernel(const float* __restrict__ qc,
                                                        const float* __restrict__ kc,
                                                        const float* __restrict__ vcp,
                                                        float* __restrict__ av)
{
  int g = blockIdx.x; int b = g >> 7; int v = g & 127;
  int tid = threadIdx.x;
  __shared__ float smem[128 * 68];         // qc rows [c][t]@130, then vc^T [t][d]@68
  __shared__ float Ps[64 * 68];            // logits/probs [c][d]@68
  size_t base = ((size_t)b * 64 << 14) + (v << 7);
  for (int f = tid; f < 8192; f += 256) {
    int c = f >> 7, t = f & 127;
    smem[c * 130 + t] = qc[base + ((size_t)c << 14) + t];
  }
  __syncthreads();
  {
    int d = tid & 63, w = tid >> 6;
    const float4* k4 = (const float4*)(kc + base + ((size_t)d << 14));
#pragma unroll 1
    for (int j = 0; j < 16; j++) {
      int c = w + (j << 2);
      const float* qrow = &smem[c * 130];
      float e = 0.f;
#pragma unroll
      for (int t4 = 0; t4 < 32; t4++) {
        float4 kv = k4[t4];
        const float* qp = qrow + (t4 << 2);
        e += qp[0] * kv.x + qp[1] * kv.y + qp[2] * kv.z + qp[3] * kv.w;
      }
      Ps[c * 68 + d] = e;
    }
  }
  __syncthreads();
  if (tid < 64) {
    int c = tid;
    float m = -1e30f;
#pragma unroll 1
    for (int d = 0; d < 64; d++) m = fmaxf(m, Ps[c * 68 + d]);
    float s = 0.f;
#pragma unroll 1
    for (int d = 0; d < 64; d++) { float p = __expf(Ps[c * 68 + d] - m); Ps[c * 68 + d] = p; s += p; }
    float inv = 1.0f / s;
#pragma unroll 1
    for (int d = 0; d < 64; d++) Ps[c * 68 + d] *= inv;
  }
  __syncthreads();
  for (int f = tid; f < 8192; f += 256) {  // stage vc transposed [t][d]
    int d = f >> 7, t = f & 127;
    smem[t * 68 + d] = vcp[base + ((size_t)d << 14) + t];
  }
  __syncthreads();
  {
    int t = tid & 127, chh = tid >> 7;
    float4 vreg[16];
    const float4* vt4 = (const float4*)&smem[t * 68];
#pragma unroll
    for (int d4 = 0; d4 < 16; d4++) vreg[d4] = vt4[d4];
#pragma unroll 1
    for (int j = 0; j < 32; j++) {
      int c = chh + (j << 1);
      const float4* p4 = (const float4*)&Ps[c * 68];
      float a = 0.f;
#pragma unroll
      for (int d4 = 0; d4 < 16; d4++) {
        float4 pv = p4[d4];
        a += pv.x * vreg[d4].x + pv.y * vreg[d4].y + pv.z * vreg[d4].z + pv.w * vreg[d4].w;
      }
      av[base + ((size_t)c << 14) + t] = a;
    }
  }
}

// ---------------- conv3x3 (bf16 MFMA) + final combine -> f32 out ---------------
// grid: (b, v-pair) = 512 blocks x 512 thr (8 waves).
// Per block: stage av rows v0-1..v0+2 as bf16 LDS [4][130][72] (d-contiguous),
// wave w -> (ch-tile mt=w&3, row r=w>>2), loops 8 col-tiles; per tile
// 9 taps x 2 = 18 mfma_f32_16x16x32_bf16, B-frag = 1 ds_read_b128 each.
__global__ __launch_bounds__(512) void conv3x3_mfma_kernel(const float* __restrict__ av,
                                                           const unsigned short* __restrict__ w2,
                                                           const float* __restrict__ y,
                                                           const float* __restrict__ X1,
                                                           const float* __restrict__ sigmaP,
                                                           float* __restrict__ out)
{
  int blk = blockIdx.x; int b = blk >> 6; int v0 = (blk & 63) << 1;
  int tid = threadIdx.x;
  __shared__ __align__(16) unsigned short avs[4 * 130 * 72];  // [r][c][d, pad 72]
  // ---- stage av -> bf16 LDS (pack 2 d per u32 write) ----
  for (int f = tid; f < 16640; f += 512) {
    int c = f % 130; int rest = f / 130; int d2 = rest & 31; int r = rest >> 5;
    int vr = v0 - 1 + r; int t = c - 1;
    float f0 = 0.f, f1 = 0.f;
    if ((unsigned)vr < 128u && (unsigned)t < 128u) {
      size_t gidx = ((size_t)(b * 64 + 2 * d2) << 14) + (vr << 7) + t;
      f0 = av[gidx]; f1 = av[gidx + 16384];
    }
    __hip_bfloat16 h0 = __float2bfloat16(f0), h1 = __float2bfloat16(f1);
    unsigned int pack = (unsigned int)(*(unsigned short*)&h0)
                      | ((unsigned int)(*(unsigned short*)&h1) << 16);
    *(unsigned int*)&avs[(r * 130 + c) * 72 + 2 * d2] = pack;
  }
  // ---- preload A-frags (weights) ----
  int lane = tid & 63; int w = tid >> 6;
  int mt = w & 3; int r = w >> 2;
  int m = mt * 16 + (lane & 15); int kb = lane >> 4;
  short8 afr[9][2];
#pragma unroll
  for (int tap = 0; tap < 9; tap++)
#pragma unroll
    for (int h = 0; h < 2; h++)
      afr[tap][h] = *(const short8*)&w2[(m * 9 + tap) * 64 + h * 32 + kb * 8];
  __syncthreads();
  float sig = sigmaP[0];
  int col16 = lane & 15;
#pragma unroll 1
  for (int ct = 0; ct < 8; ct++) {
    f32x4 acc = {0.f, 0.f, 0.f, 0.f};
#pragma unroll
    for (int dv = 0; dv < 3; dv++) {
#pragma unroll
      for (int dt = 0; dt < 3; dt++) {
        int lrow = r + dv;
        int lcol = ct * 16 + col16 + dt;
        const unsigned short* base = &avs[(lrow * 130 + lcol) * 72 + kb * 8];
#pragma unroll
        for (int h = 0; h < 2; h++) {
          short8 bfr = *(const short8*)&base[h * 32];
          acc = __builtin_amdgcn_mfma_f32_16x16x32_bf16(afr[dv * 3 + dt][h], bfr, acc, 0, 0, 0);
        }
      }
    }
    int posc = ct * 16 + col16;
#pragma unroll
    for (int reg = 0; reg < 4; reg++) {
      int ch = mt * 16 + kb * 4 + reg;
      size_t idx = ((size_t)(b * 64 + ch) << 14) + ((v0 + r) << 7) + posc;
      out[idx] = y[idx] + X1[idx] + sig * acc[reg];
    }
  }
}

} // namespace

extern "C" void kernel_launch(void* const* d_in, const int* in_sizes, int n_in,
                              void* d_out, int out_size, void* d_ws, size_t ws_size,
                              hipStream_t stream)
{
  (void)in_sizes; (void)n_in; (void)out_size;
  const float* x     = (const float*)d_in[0];
  const float* dcw   = (const float*)d_in[1];
  const float* dcb   = (const float*)d_in[2];
  const float* qw    = (const float*)d_in[3];
  const float* qbb   = (const float*)d_in[4];
  const float* kw    = (const float*)d_in[5];
  const float* kbb   = (const float*)d_in[6];
  const float* vw    = (const float*)d_in[7];
  const float* vbb   = (const float*)d_in[8];
  const float* gamma = (const float*)d_in[9];
  const float* cqw   = (const float*)d_in[10];
  const float* cqb   = (const float*)d_in[11];
  const float* ckw   = (const float*)d_in[12];
  const float* ckb   = (const float*)d_in[13];
  const float* cvw   = (const float*)d_in[14];
  const float* cvb   = (const float*)d_in[15];
  const float* avw   = (const float*)d_in[16];
  const float* sigma = (const float*)d_in[17];
  float* out = (float*)d_out;

  if (ws_size < 220348416ull) return;      // need ~210 MiB of f32 scratch

  float* ws  = (float*)d_ws;
  float* y   = ws;                         // (b,c,v,t)   8,388,608
  float* X1  = ws + 8388608;               // (b,c,v,t)
  float* q   = ws + 16777216;              // (b,8,v,t)
  float* k   = ws + 17825792;
  float* qT  = ws + 18874368;              // (b,t,8,v)
  float* kT  = ws + 19922944;
  float* v   = ws + 20971520;              // (b,c,v,t)
  float* vT  = ws + 29360128;              // (b,t,c,u)
  float* UH  = ws + 37748736;              // (b,t,v,c)
  float* UW  = ws + 46137344;              // (b,v,t,c)
  float* mH  = ws + 54525952;              // (b,t,v)
  float* sH  = ws + 54657024;
  float* mW  = ws + 54788096;              // (b,v,t)
  float* sW  = ws + 54919168;
  unsigned short* w2 = (unsigned short*)(ws + 55050240);  // 36,864 bf16 conv3x3 weights
  float* qc  = vT;                         // reuse (consumed before reuse)
  float* kc  = UH;
  float* vc  = UW;
  float* avb = v;

  prep_w_kernel<<<144, 256, 0, stream>>>(avw, w2);
  dc_conv_kernel<<<1024, 256, 0, stream>>>(x, dcw, dcb, y);
  conv1x1_kernel<8,  true ><<<1024, 256, 0, stream>>>(y, qw,  qbb, q,  qT);
  conv1x1_kernel<8,  true ><<<1024, 256, 0, stream>>>(y, kw,  kbb, k,  kT);
  conv1x1_kernel<64, true ><<<1024, 256, 0, stream>>>(y, vw,  vbb, v,  vT);
  // Stage A: per (b,t), qT/kT (b,t,c,v): QB=131072 QI=1024 QC=128; vT: VB=1048576 VI=8192 VC=128
  attn_stage_kernel<true ><<<1024, 256, 0, stream>>>(qT, kT, vT,
      131072, 1024, 128, 1048576, 8192, 128, UH, mH, sH);
  // Stage B: per (b,v), q/k (b,c,v,t): QB=131072 QI=128 QC=16384; v: VB=1048576 VI=128 VC=16384
  attn_stage_kernel<false><<<1024, 256, 0, stream>>>(q, k, v,
      131072, 128, 16384, 1048576, 128, 16384, UW, mW, sW);
  stage_c_kernel<<<1024, 256, 0, stream>>>(UH, UW, mH, sH, mW, sW, gamma, X1);
  conv1x1_kernel<64, false><<<1024, 256, 0, stream>>>(y, cqw, cqb, qc, (float*)nullptr);
  conv1x1_kernel<64, false><<<1024, 256, 0, stream>>>(y, ckw, ckb, kc, (float*)nullptr);
  conv1x1_kernel<64, false><<<1024, 256, 0, stream>>>(y, cvw, cvb, vc, (float*)nullptr);
  chan_attn_kernel<<<1024, 256, 0, stream>>>(qc, kc, vc, avb);
  conv3x3_mfma_kernel<<<512, 512, 0, stream>>>(avb, w2, y, X1, sigma, out);
}

// Round 9
// 763.679 us; speedup vs baseline: 1.7787x; 1.3594x over previous
//
#include <hip/hip_runtime.h>
#include <hip/hip_bf16.h>

// ParallelCAttention on MI355X. All device I/O is f32 (matches reference dtype).
// B=8, CIN=256, COUT=64, CQK=8, padded V=T=128 (V0=T0=126).
//
// R8: fuse {qc,kc,vc conv1x1 + channel attention} into one MFMA kernel
//     (per (b,v) slice; 5 GEMM phases + wave-parallel softmax, LDS pool
//     with phase aliasing). Deletes 3 conv1x1<64> launches + chan_attn.
// R7: conv3x3 -> bf16 MFMA. R6/R5: conv re-grids.

namespace {

using short8 = __attribute__((ext_vector_type(8))) short;
using f32x4  = __attribute__((ext_vector_type(4))) float;

// ---------------- prep weights for conv3x3 (bf16, [o][tap][i]) ----------------
__global__ __launch_bounds__(256) void prep_w_kernel(const float* __restrict__ avw,
                                                     unsigned short* __restrict__ w2)
{
  int idx = blockIdx.x * 256 + threadIdx.x;
  if (idx >= 64 * 64 * 9) return;
  int o = idx / 576; int rem = idx - o * 576;
  int i = rem / 9;   int tap = rem - i * 9;
  __hip_bfloat16 h = __float2bfloat16(avw[idx]);
  w2[(o * 9 + tap) * 64 + i] = *(unsigned short*)&h;
}

// ---------------- y = conv1x1(pad(x), dc_w) + dc_b ----------------
// grid: (b, v) = 1024 blocks; 256 thr = 128 cols x 2 out-ch halves (32 each)
__global__ __launch_bounds__(256) void dc_conv_kernel(const float* __restrict__ x,
                                                      const float* __restrict__ w,
                                                      const float* __restrict__ bias,
                                                      float* __restrict__ y)
{
  int blk = blockIdx.x; int b = blk >> 7; int v = blk & 127;
  int tid = threadIdx.x;
  int tt = tid & 127; int sub = tid >> 7;  // sub: out-channel half
  bool interior = (v >= 1) && (v <= 126) && (tt >= 1) && (tt <= 126);
  __shared__ float xs[8 * 128];
  __shared__ float wsh[8 * 64];            // [i][o]
  float acc[32];
#pragma unroll
  for (int o = 0; o < 32; o++) acc[o] = 0.f;
  size_t xrow = (size_t)b * 256 * 15876 + (size_t)(v - 1) * 126;
#pragma unroll 1
  for (int cc = 0; cc < 256; cc += 8) {
    for (int f = tid; f < 1024; f += 256) {
      int i = f >> 7; int col = f & 127;
      float val = 0.f;
      if ((v >= 1) && (v <= 126) && (col >= 1) && (col <= 126))
        val = x[xrow + (size_t)(cc + i) * 15876 + (col - 1)];
      xs[f] = val;
    }
    for (int f = tid; f < 512; f += 256) {
      int i = f >> 6; int o = f & 63;
      wsh[i * 64 + o] = w[o * 256 + cc + i];
    }
    __syncthreads();
    if (interior) {
#pragma unroll
      for (int i = 0; i < 8; i++) {
        float a = xs[i * 128 + tt];
        const float4* w4 = (const float4*)&wsh[i * 64 + sub * 32];
#pragma unroll
        for (int o4 = 0; o4 < 8; o4++) {
          float4 wv = w4[o4];
          acc[o4 * 4 + 0] += a * wv.x; acc[o4 * 4 + 1] += a * wv.y;
          acc[o4 * 4 + 2] += a * wv.z; acc[o4 * 4 + 3] += a * wv.w;
        }
      }
    }
    __syncthreads();
  }
  int p = (v << 7) + tt;
  float* yb = y + ((size_t)b * 64 << 14) + p;
#pragma unroll
  for (int o = 0; o < 32; o++) {
    int oc = sub * 32 + o;
    yb[(size_t)oc << 14] = acc[o] + bias[oc];
  }
}

// ---------------- generic conv1x1 from y (f32 in, f32 out, 64-ch input) -------
// grid: (b, v) = 1024 blocks; 256 thr = 128 cols x 2 out-ch halves (O/2 each)
template <int O, bool WRITE_T>
__global__ __launch_bounds__(256) void conv1x1_kernel(const float* __restrict__ in,
                                                      const float* __restrict__ w,
                                                      const float* __restrict__ bias,
                                                      float* __restrict__ out,
                                                      float* __restrict__ outT)
{
  constexpr int OH = O / 2;
  int blk = blockIdx.x; int b = blk >> 7; int v = blk & 127;
  int tid = threadIdx.x;
  int tt = tid & 127; int sub = tid >> 7;
  int p = (v << 7) + tt;
  __shared__ float ys[8 * 128];
  __shared__ float wsh[8 * O];             // [i][o]
  float acc[OH];
#pragma unroll
  for (int o = 0; o < OH; o++) acc[o] = 0.f;
  const float* inb = in + ((size_t)b * 64 << 14) + (v << 7);
#pragma unroll 1
  for (int cc = 0; cc < 64; cc += 8) {
    for (int f = tid; f < 1024; f += 256) {
      int i = f >> 7; int col = f & 127;
      ys[f] = inb[((size_t)(cc + i) << 14) + col];
    }
    for (int f = tid; f < 8 * O; f += 256) {
      int i = f / O; int o = f - i * O;
      wsh[f] = w[o * 64 + cc + i];
    }
    __syncthreads();
#pragma unroll
    for (int i = 0; i < 8; i++) {
      float a = ys[i * 128 + tt];
      const float4* w4 = (const float4*)&wsh[i * O + sub * OH];
#pragma unroll
      for (int o4 = 0; o4 < OH / 4; o4++) {
        float4 wv = w4[o4];
        acc[o4 * 4 + 0] += a * wv.x; acc[o4 * 4 + 1] += a * wv.y;
        acc[o4 * 4 + 2] += a * wv.z; acc[o4 * 4 + 3] += a * wv.w;
      }
    }
    __syncthreads();
  }
#pragma unroll
  for (int o = 0; o < OH; o++) {
    int oc = sub * OH + o;
    float r = acc[o] + bias[oc];
    out[((size_t)(b * O + oc) << 14) + p] = r;
    if (WRITE_T) outT[(((size_t)(b * 128 + tt) * O + oc) << 7) + v] = r;  // (b,t,c,pos)
  }
}

// ---------------- flash-style attention stage (shared for H and W axes) -------
template <bool MASK>
__global__ __launch_bounds__(256) void attn_stage_kernel(const float* __restrict__ qP,
                                                         const float* __restrict__ kP,
                                                         const float* __restrict__ vP,
                                                         int QB, int QI, int QC,
                                                         int VB, int VI, int VC,
                                                         float* __restrict__ U,
                                                         float* __restrict__ mG,
                                                         float* __restrict__ sG)
{
  int g = blockIdx.x; int b = g >> 7; int ii = g & 127;
  int tid = threadIdx.x;
  __shared__ float qsT[128 * 12];          // [pos][c], stride 12 (16B-aligned rows)
  __shared__ float ksT[128 * 12];
  __shared__ float Ps[32 * 132];           // P chunk, stride 132 (16B-aligned rows)
  __shared__ float ms[128];
  const float* qb = qP + (size_t)b * QB + (size_t)ii * QI;
  const float* kb = kP + (size_t)b * QB + (size_t)ii * QI;
  for (int f = tid; f < 1024; f += 256) {
    int c = f >> 7; int j = f & 127;
    qsT[j * 12 + c] = qb[(size_t)c * QC + j];
    ksT[j * 12 + c] = kb[(size_t)c * QC + j];
  }
  __syncthreads();
  {
    int r = tid >> 1; int half = tid & 1; int u0 = half << 6;
    float4 qa  = *(const float4*)&qsT[r * 12];
    float4 qb4 = *(const float4*)&qsT[r * 12 + 4];
    float mloc = -1e30f;
    for (int du = 0; du < 64; du++) {
      int u = u0 + du;
      const float4* kp = (const float4*)&ksT[u * 12];
      float4 ka = kp[0], kb2 = kp[1];
      float e = qa.x * ka.x + qa.y * ka.y + qa.z * ka.z + qa.w * ka.w
              + qb4.x * kb2.x + qb4.y * kb2.y + qb4.z * kb2.z + qb4.w * kb2.w;
      if (!(MASK && u == r)) mloc = fmaxf(mloc, e);
    }
    float M = fmaxf(mloc, __shfl_xor(mloc, 1));
    float sloc = 0.f;
    for (int du = 0; du < 64; du++) {
      int u = u0 + du;
      const float4* kp = (const float4*)&ksT[u * 12];
      float4 ka = kp[0], kb2 = kp[1];
      float e = qa.x * ka.x + qa.y * ka.y + qa.z * ka.z + qa.w * ka.w
              + qb4.x * kb2.x + qb4.y * kb2.y + qb4.z * kb2.z + qb4.w * kb2.w;
      if (!(MASK && u == r)) sloc += __expf(e - M);
    }
    float stot = sloc + __shfl_xor(sloc, 1);
    if (half == 0) { ms[r] = M; mG[(g << 7) + r] = M; sG[(g << 7) + r] = stot; }
  }
  __syncthreads();
  int c = tid & 63; int w = tid >> 6;
  const float4* v4 = (const float4*)(vP + (size_t)b * VB + (size_t)ii * VI + (size_t)c * VC);
  float acc[32];
#pragma unroll
  for (int j = 0; j < 32; j++) acc[j] = 0.f;
#pragma unroll
  for (int chk = 0; chk < 4; chk++) {
    int rbase = chk << 5;
    for (int f = tid; f < 4096; f += 256) {
      int rr = f >> 7; int u = f & 127; int r = rbase + rr;
      const float4* qp = (const float4*)&qsT[r * 12];
      const float4* kp = (const float4*)&ksT[u * 12];
      float4 qa = qp[0], qb4 = qp[1], ka = kp[0], kb2 = kp[1];
      float e = qa.x * ka.x + qa.y * ka.y + qa.z * ka.z + qa.w * ka.w
              + qb4.x * kb2.x + qb4.y * kb2.y + qb4.z * kb2.z + qb4.w * kb2.w;
      float pv;
      if (MASK && u == r) pv = 0.f; else pv = __expf(e - ms[r]);
      Ps[rr * 132 + u] = pv;
    }
    __syncthreads();
    for (int u4 = 0; u4 < 32; u4++) {
      float4 vvv = v4[u4];
      int ub = u4 << 2;
#pragma unroll
      for (int jj = 0; jj < 8; jj++) {
        const float* pr = &Ps[(w + (jj << 2)) * 132 + ub];
        acc[(chk << 3) + jj] += pr[0] * vvv.x + pr[1] * vvv.y + pr[2] * vvv.z + pr[3] * vvv.w;
      }
    }
    __syncthreads();
  }
#pragma unroll
  for (int j = 0; j < 32; j++) {
    int c2 = j >> 3; int jj = j & 7;
    int r = (c2 << 5) + w + (jj << 2);
    U[((size_t)(g << 7) + r) * 64 + c] = acc[j];
  }
}

// ---------------- joint-softmax merge: X1 = gamma*(out_H+out_W) ----------------
__global__ __launch_bounds__(256) void stage_c_kernel(const float* __restrict__ UH,
                                                      const float* __restrict__ UW,
                                                      const float* __restrict__ mH,
                                                      const float* __restrict__ sH,
                                                      const float* __restrict__ mW,
                                                      const float* __restrict__ sW,
                                                      const float* __restrict__ gammaP,
                                                      float* __restrict__ X1)
{
  int g = blockIdx.x; int b = g >> 7; int v = g & 127;
  int tid = threadIdx.x; int t = tid & 127; int c0 = tid >> 7;
  float gam = gammaP[0];
  int idxH = ((b << 7) + t) * 128 + v;     // (b,t,v)
  int idxW = (g << 7) + t;                 // (b,v,t)
  float mh = mH[idxH], sh = sH[idxH];
  float mw = mW[idxW], sw = sW[idxW];
  float M = fmaxf(mh, mw);
  float ea = __expf(mh - M), eb = __expf(mw - M);
  float denom = sh * ea + sw * eb;
  float fA = gam * ea / denom, fB = gam * eb / denom;
  const float* uh = UH + (size_t)idxH * 64;
  const float* uw = UW + (size_t)idxW * 64;
  float* x1p = X1 + ((size_t)b * 64 << 14) + (v << 7) + t;
#pragma unroll
  for (int j = 0; j < 32; j++) {
    int c = c0 + (j << 1);
    x1p[(size_t)c << 14] = fA * uh[c] + fB * uw[c];
  }
}

// ---------------- fused channel attention (MFMA) -------------------------------
// grid: (b,v) = 1024 blocks x 256 thr (4 waves). Per block:
//  P0: stage y slice -> bf16 Y[t][c]@72
//  P1: qc/kc (->[o][t]@136) and vc (->VT[t][d]@72), 3 GEMMs M64 N128 K64
//  P2: logits[c][d] = qc.kc^T over t (K=128) -> f32 LG[c][d]@68 (aliases Y)
//  P3: wave-parallel softmax over d -> bf16 AT[c][d]@72 (aliases QC)
//  P4: av[c][t] = AT @ VT (K=64) -> global
__global__ __launch_bounds__(256) void fused_chan_attn_kernel(
    const float* __restrict__ y,
    const float* __restrict__ cqw, const float* __restrict__ cqb,
    const float* __restrict__ ckw, const float* __restrict__ ckb,
    const float* __restrict__ cvw, const float* __restrict__ cvb,
    float* __restrict__ av)
{
  int g = blockIdx.x; int b = g >> 7; int v = g & 127;
  int tid = threadIdx.x;
  int lane = tid & 63; int w = tid >> 6;   // wave id = m-tile
  int mt = w;
  int row16 = lane & 15; int kb8 = lane >> 4;
  __shared__ __align__(16) unsigned short pool[35840];
  unsigned short* Y  = pool;               // [t(128)][c@72]  9216
  unsigned short* QC = pool + 9216;        // [o(64)][t@136]  8704
  unsigned short* KC = pool + 17920;       // [o(64)][t@136]  8704
  unsigned short* VT = pool + 26624;       // [t(128)][d@72]  9216
  float*          LG = (float*)pool;       // [c(64)][d@68] f32 (alias Y)
  unsigned short* AT = QC;                 // [c(64)][d@72] bf16 (alias QC)

  // ---- P0: stage Y ----
  const float* yb = y + ((size_t)b * 64 << 14) + (v << 7);
  for (int f = tid; f < 8192; f += 256) {
    int c = f >> 7; int t = f & 127;
    __hip_bfloat16 h = __float2bfloat16(yb[((size_t)c << 14) + t]);
    Y[t * 72 + c] = *(unsigned short*)&h;
  }
  __syncthreads();

  int o_frag = mt * 16 + row16;            // A-frag row (m = lane&15)
  int orow0  = mt * 16 + (kb8 << 2);       // C/D rows (m = (lane>>4)*4+reg)
  float bq[4], bk[4], bv[4];
#pragma unroll
  for (int r = 0; r < 4; r++) {
    bq[r] = cqb[orow0 + r]; bk[r] = ckb[orow0 + r]; bv[r] = cvb[orow0 + r];
  }
  auto loadW = [&](const float* W, int kh) {
    short8 a;
    const float* p = W + o_frag * 64 + kh * 32 + kb8 * 8;
#pragma unroll
    for (int j = 0; j < 8; j++) {
      __hip_bfloat16 h = __float2bfloat16(p[j]);
      a[j] = *(short*)&h;
    }
    return a;
  };

  // ---- P1: qc, kc -> [o][t]; vc -> VT[t][d] ----
  {
    short8 aq0 = loadW(cqw, 0), aq1 = loadW(cqw, 1);
    short8 ak0 = loadW(ckw, 0), ak1 = loadW(ckw, 1);
    short8 av0 = loadW(cvw, 0), av1 = loadW(cvw, 1);
#pragma unroll 1
    for (int nt = 0; nt < 8; nt++) {
      int trow = nt * 16 + row16;
      short8 b0 = *(const short8*)&Y[trow * 72 + kb8 * 8];
      short8 b1 = *(const short8*)&Y[trow * 72 + 32 + kb8 * 8];
      f32x4 accq = {0.f,0.f,0.f,0.f}, acck = {0.f,0.f,0.f,0.f}, accv = {0.f,0.f,0.f,0.f};
      accq = __builtin_amdgcn_mfma_f32_16x16x32_bf16(aq0, b0, accq, 0, 0, 0);
      accq = __builtin_amdgcn_mfma_f32_16x16x32_bf16(aq1, b1, accq, 0, 0, 0);
      acck = __builtin_amdgcn_mfma_f32_16x16x32_bf16(ak0, b0, acck, 0, 0, 0);
      acck = __builtin_amdgcn_mfma_f32_16x16x32_bf16(ak1, b1, acck, 0, 0, 0);
      accv = __builtin_amdgcn_mfma_f32_16x16x32_bf16(av0, b0, accv, 0, 0, 0);
      accv = __builtin_amdgcn_mfma_f32_16x16x32_bf16(av1, b1, accv, 0, 0, 0);
      int tc = nt * 16 + row16;            // D col = lane&15
#pragma unroll
      for (int r = 0; r < 4; r++) {
        __hip_bfloat16 hq = __float2bfloat16(accq[r] + bq[r]);
        __hip_bfloat16 hk = __float2bfloat16(acck[r] + bk[r]);
        __hip_bfloat16 hv = __float2bfloat16(accv[r] + bv[r]);
        QC[(orow0 + r) * 136 + tc] = *(unsigned short*)&hq;
        KC[(orow0 + r) * 136 + tc] = *(unsigned short*)&hk;
        VT[tc * 72 + orow0 + r]    = *(unsigned short*)&hv;
      }
    }
  }
  __syncthreads();

  // ---- P2: logits[c][d] over t (K=128) ----
#pragma unroll 1
  for (int nt = 0; nt < 4; nt++) {
    f32x4 acc = {0.f,0.f,0.f,0.f};
#pragma unroll
    for (int kh = 0; kh < 4; kh++) {
      int k0 = kh * 32 + kb8 * 8;
      short8 a = *(const short8*)&QC[(mt * 16 + row16) * 136 + k0];
      short8 bb = *(const short8*)&KC[(nt * 16 + row16) * 136 + k0];
      acc = __builtin_amdgcn_mfma_f32_16x16x32_bf16(a, bb, acc, 0, 0, 0);
    }
#pragma unroll
    for (int r = 0; r < 4; r++)
      LG[(orow0 + r) * 68 + nt * 16 + row16] = acc[r];
  }
  __syncthreads();

  // ---- P3: softmax over d (4 lanes per row) -> AT bf16 ----
  {
    int c = tid >> 2; int q4 = tid & 3;
    float vals[16];
    const float* lr = &LG[c * 68 + q4 * 16];
    float m = -1e30f;
#pragma unroll
    for (int j = 0; j < 16; j++) { vals[j] = lr[j]; m = fmaxf(m, vals[j]); }
    m = fmaxf(m, __shfl_xor(m, 1)); m = fmaxf(m, __shfl_xor(m, 2));
    float s = 0.f;
#pragma unroll
    for (int j = 0; j < 16; j++) { vals[j] = __expf(vals[j] - m); s += vals[j]; }
    s += __shfl_xor(s, 1); s += __shfl_xor(s, 2);
    float inv = 1.0f / s;
    __syncthreads();                        // QC dead after P2; AT may overwrite
#pragma unroll
    for (int j = 0; j < 16; j++) {
      __hip_bfloat16 h = __float2bfloat16(vals[j] * inv);
      AT[c * 72 + q4 * 16 + j] = *(unsigned short*)&h;
    }
  }
  __syncthreads();

  // ---- P4: av[c][t] = AT @ VT (K=64) -> global ----
  float* avb = av + ((size_t)b * 64 << 14) + (v << 7);
#pragma unroll 1
  for (int nt = 0; nt < 8; nt++) {
    f32x4 acc = {0.f,0.f,0.f,0.f};
#pragma unroll
    for (int kh = 0; kh < 2; kh++) {
      int k0 = kh * 32 + kb8 * 8;
      short8 a = *(const short8*)&AT[(mt * 16 + row16) * 72 + k0];
      short8 bb = *(const short8*)&VT[(nt * 16 + row16) * 72 + k0];
      acc = __builtin_amdgcn_mfma_f32_16x16x32_bf16(a, bb, acc, 0, 0, 0);
    }
    int tc = nt * 16 + row16;
#pragma unroll
    for (int r = 0; r < 4; r++)
      avb[((size_t)(orow0 + r) << 14) + tc] = acc[r];
  }
}

// ---------------- conv3x3 (bf16 MFMA) + final combine -> f32 out ---------------
// grid: (b, v-pair) = 512 blocks x 512 thr (8 waves).
__global__ __launch_bounds__(512) void conv3x3_mfma_kernel(const float* __restrict__ av,
                                                           const unsigned short* __restrict__ w2,
                                                           const float* __restrict__ y,
                                                           const float* __restrict__ X1,
                                                           const float* __restrict__ sigmaP,
                                                           float* __restrict__ out)
{
  int blk = blockIdx.x; int b = blk >> 6; int v0 = (blk & 63) << 1;
  int tid = threadIdx.x;
  __shared__ __align__(16) unsigned short avs[4 * 130 * 72];  // [r][c][d, pad 72]
  for (int f = tid; f < 16640; f += 512) {
    int c = f % 130; int rest = f / 130; int d2 = rest & 31; int r = rest >> 5;
    int vr = v0 - 1 + r; int t = c - 1;
    float f0 = 0.f, f1 = 0.f;
    if ((unsigned)vr < 128u && (unsigned)t < 128u) {
      size_t gidx = ((size_t)(b * 64 + 2 * d2) << 14) + (vr << 7) + t;
      f0 = av[gidx]; f1 = av[gidx + 16384];
    }
    __hip_bfloat16 h0 = __float2bfloat16(f0), h1 = __float2bfloat16(f1);
    unsigned int pack = (unsigned int)(*(unsigned short*)&h0)
                      | ((unsigned int)(*(unsigned short*)&h1) << 16);
    *(unsigned int*)&avs[(r * 130 + c) * 72 + 2 * d2] = pack;
  }
  int lane = tid & 63; int w = tid >> 6;
  int mt = w & 3; int r = w >> 2;
  int m = mt * 16 + (lane & 15); int kb = lane >> 4;
  short8 afr[9][2];
#pragma unroll
  for (int tap = 0; tap < 9; tap++)
#pragma unroll
    for (int h = 0; h < 2; h++)
      afr[tap][h] = *(const short8*)&w2[(m * 9 + tap) * 64 + h * 32 + kb * 8];
  __syncthreads();
  float sig = sigmaP[0];
  int col16 = lane & 15;
#pragma unroll 1
  for (int ct = 0; ct < 8; ct++) {
    f32x4 acc = {0.f, 0.f, 0.f, 0.f};
#pragma unroll
    for (int dv = 0; dv < 3; dv++) {
#pragma unroll
      for (int dt = 0; dt < 3; dt++) {
        int lrow = r + dv;
        int lcol = ct * 16 + col16 + dt;
        const unsigned short* base = &avs[(lrow * 130 + lcol) * 72 + kb * 8];
#pragma unroll
        for (int h = 0; h < 2; h++) {
          short8 bfr = *(const short8*)&base[h * 32];
          acc = __builtin_amdgcn_mfma_f32_16x16x32_bf16(afr[dv * 3 + dt][h], bfr, acc, 0, 0, 0);
        }
      }
    }
    int posc = ct * 16 + col16;
#pragma unroll
    for (int reg = 0; reg < 4; reg++) {
      int ch = mt * 16 + kb * 4 + reg;
      size_t idx = ((size_t)(b * 64 + ch) << 14) + ((v0 + r) << 7) + posc;
      out[idx] = y[idx] + X1[idx] + sig * acc[reg];
    }
  }
}

} // namespace

extern "C" void kernel_launch(void* const* d_in, const int* in_sizes, int n_in,
                              void* d_out, int out_size, void* d_ws, size_t ws_size,
                              hipStream_t stream)
{
  (void)in_sizes; (void)n_in; (void)out_size;
  const float* x     = (const float*)d_in[0];
  const float* dcw   = (const float*)d_in[1];
  const float* dcb   = (const float*)d_in[2];
  const float* qw    = (const float*)d_in[3];
  const float* qbb   = (const float*)d_in[4];
  const float* kw    = (const float*)d_in[5];
  const float* kbb   = (const float*)d_in[6];
  const float* vw    = (const float*)d_in[7];
  const float* vbb   = (const float*)d_in[8];
  const float* gamma = (const float*)d_in[9];
  const float* cqw   = (const float*)d_in[10];
  const float* cqb   = (const float*)d_in[11];
  const float* ckw   = (const float*)d_in[12];
  const float* ckb   = (const float*)d_in[13];
  const float* cvw   = (const float*)d_in[14];
  const float* cvb   = (const float*)d_in[15];
  const float* avw   = (const float*)d_in[16];
  const float* sigma = (const float*)d_in[17];
  float* out = (float*)d_out;

  if (ws_size < 220348416ull) return;      // need ~210 MiB of f32 scratch

  float* ws  = (float*)d_ws;
  float* y   = ws;                         // (b,c,v,t)   8,388,608
  float* X1  = ws + 8388608;               // (b,c,v,t)
  float* q   = ws + 16777216;              // (b,8,v,t)
  float* k   = ws + 17825792;
  float* qT  = ws + 18874368;              // (b,t,8,v)
  float* kT  = ws + 19922944;
  float* v   = ws + 20971520;              // (b,c,v,t)
  float* vT  = ws + 29360128;              // (b,t,c,u)
  float* UH  = ws + 37748736;              // (b,t,v,c)
  float* UW  = ws + 46137344;              // (b,v,t,c)
  float* mH  = ws + 54525952;              // (b,t,v)
  float* sH  = ws + 54657024;
  float* mW  = ws + 54788096;              // (b,v,t)
  float* sW  = ws + 54919168;
  unsigned short* w2 = (unsigned short*)(ws + 55050240);  // 36,864 bf16 conv3x3 weights
  float* avb = v;                          // reuse (v consumed by attn stage B)

  prep_w_kernel<<<144, 256, 0, stream>>>(avw, w2);
  dc_conv_kernel<<<1024, 256, 0, stream>>>(x, dcw, dcb, y);
  conv1x1_kernel<8,  true ><<<1024, 256, 0, stream>>>(y, qw,  qbb, q,  qT);
  conv1x1_kernel<8,  true ><<<1024, 256, 0, stream>>>(y, kw,  kbb, k,  kT);
  conv1x1_kernel<64, true ><<<1024, 256, 0, stream>>>(y, vw,  vbb, v,  vT);
  // Stage A: per (b,t), qT/kT (b,t,c,v): QB=131072 QI=1024 QC=128; vT: VB=1048576 VI=8192 VC=128
  attn_stage_kernel<true ><<<1024, 256, 0, stream>>>(qT, kT, vT,
      131072, 1024, 128, 1048576, 8192, 128, UH, mH, sH);
  // Stage B: per (b,v), q/k (b,c,v,t): QB=131072 QI=128 QC=16384; v: VB=1048576 VI=128 VC=16384
  attn_stage_kernel<false><<<1024, 256, 0, stream>>>(q, k, v,
      131072, 128, 16384, 1048576, 128, 16384, UW, mW, sW);
  stage_c_kernel<<<1024, 256, 0, stream>>>(UH, UW, mH, sH, mW, sW, gamma, X1);
  fused_chan_attn_kernel<<<1024, 256, 0, stream>>>(y, cqw, cqb, ckw, ckb, cvw, cvb, avb);
  conv3x3_mfma_kernel<<<512, 512, 0, stream>>>(avb, w2, y, X1, sigma, out);
}